// Round 9
// baseline (186.882 us; speedup 1.0000x reference)
//
#include <hip/hip_runtime.h>

// x (32,256,56,56) f32, cols (64,4) i32. Per (b,g,w,h): among the 4 channels
// cols[g,:], keep only the FIRST max (jnp.argmax tie-break), zero the rest,
// then ReLU. cols covers all 256 channels, so every output elem is written.
//
// Structure: one block per (b,g). Phase 1: stage the 4 channel planes
// (4 x 12544B) into LDS as a pure-read linear sweep (13 independent loads
// per thread, block-wide ~4KB contiguous front per plane). Phase 2: compute
// from LDS and stream the 4 output planes as a pure-write phase. This
// collapses per-CU concurrent DRAM streams (~40 mixed r/w -> ~3 phase-pure)
// to mimic the access shape of the 6.3+ TB/s copy/fill kernels.
constexpr int B  = 32;
constexpr int C  = 256;
constexpr int P  = 56 * 56;      // 3136 elems per plane (12544 B)
constexpr int G  = 64;
constexpr int GS = 4;
constexpr int F  = P / 4;        // 784 float4 per plane
constexpr int BLOCK = 256;
constexpr int BLOCKS = B * G;    // 2048 blocks, one per (b,g)

typedef float fx4 __attribute__((ext_vector_type(4)));

__global__ __launch_bounds__(BLOCK) void cgm_kernel(const float* __restrict__ x,
                                                    const int* __restrict__ cols,
                                                    float* __restrict__ out) {
    __shared__ float lds[GS * P];   // 50176 B -> 3 blocks/CU

    int t = threadIdx.x;
    int g = blockIdx.x & (G - 1);
    int b = blockIdx.x >> 6;

    long base[GS];
#pragma unroll
    for (int s = 0; s < GS; ++s) {
        int c = cols[g * GS + s];
        base[s] = ((long)b * C + c) * (long)P;
    }

    // ---- Phase 1: pure-read linear staging (13 independent 16B loads) ----
#pragma unroll
    for (int s = 0; s < GS; ++s) {
#pragma unroll
        for (int i = 0; i < 4; ++i) {
            int u4 = i * BLOCK + t;           // float4 index in plane, < 784
            if (u4 < F) {
                fx4 v = *reinterpret_cast<const fx4*>(x + base[s] + (long)u4 * 4);
                *reinterpret_cast<fx4*>(&lds[s * P + u4 * 4]) = v;
            }
        }
    }

    __syncthreads();

    // ---- Phase 2: compute from LDS, pure-write streaming ----
#pragma unroll
    for (int i = 0; i < 4; ++i) {
        int u4 = i * BLOCK + t;
        if (u4 < F) {
            fx4 v[GS];
#pragma unroll
            for (int s = 0; s < GS; ++s)
                v[s] = *reinterpret_cast<const fx4*>(&lds[s * P + u4 * 4]);

            fx4 o[GS];
#pragma unroll
            for (int s = 0; s < GS; ++s) o[s] = (fx4)0.0f;

            // Component-wise argmax, FIRST-max tie-break (strict >), then ReLU.
#pragma unroll
            for (int j = 0; j < 4; ++j) {
                int   bi   = 0;
                float best = v[0][j];
#pragma unroll
                for (int s = 1; s < GS; ++s) {
                    if (v[s][j] > best) { best = v[s][j]; bi = s; }
                }
                float r = best > 0.0f ? best : 0.0f;
#pragma unroll
                for (int s = 0; s < GS; ++s) {
                    if (s == bi) o[s][j] = r;
                }
            }

#pragma unroll
            for (int s = 0; s < GS; ++s)
                *reinterpret_cast<fx4*>(out + base[s] + (long)u4 * 4) = o[s];
        }
    }
}

extern "C" void kernel_launch(void* const* d_in, const int* in_sizes, int n_in,
                              void* d_out, int out_size, void* d_ws, size_t ws_size,
                              hipStream_t stream) {
    const float* x    = (const float*)d_in[0];
    const int*   cols = (const int*)d_in[1];
    float*       out  = (float*)d_out;

    cgm_kernel<<<dim3(BLOCKS), dim3(BLOCK), 0, stream>>>(x, cols, out);
}